// Round 9
// baseline (235.433 us; speedup 1.0000x reference)
//
#include <hip/hip_runtime.h>
#include <hip/hip_bf16.h>

typedef unsigned short u16;
typedef unsigned int u32;
typedef short bf16x8 __attribute__((ext_vector_type(8)));
typedef float f32x4 __attribute__((ext_vector_type(4)));

#define AS1 __attribute__((address_space(1)))
#define AS3 __attribute__((address_space(3)))

#define NTOK 4096
#define HDIM 512
#define FDIM 2048
#define NEXP 8
#define NASSIGN (NTOK * 2)
#define NPAD (NASSIGN + NEXP * 128)  // 9216
#define RBMAX 128

__device__ __forceinline__ void g2l16(const void* g, void* l) {
  __builtin_amdgcn_global_load_lds((const AS1 u32*)g, (AS3 u32*)l, 16, 0, 0);
}
__device__ __forceinline__ u16 f2bf(float f) {  // RNE fp32->bf16
  u32 u = __float_as_uint(f);
  u = (u + 0x7FFFu + ((u >> 16) & 1u)) >> 16;
  return (u16)u;
}
__device__ __forceinline__ float bf2f(u16 h) { return __uint_as_float(((u32)h) << 16); }
__device__ __forceinline__ u32 pkbf(float a, float b) {  // v_cvt_pk_bf16_f32 (RNE)
  __hip_bfloat162 h = __float22bfloat162_rn(float2{a, b});
  u32 r;
  __builtin_memcpy(&r, &h, 4);
  return r;
}
__device__ __forceinline__ int4 pk8(const float4 a, const float4 b) {
  int4 r;
  r.x = (int)pkbf(a.x, a.y); r.y = (int)pkbf(a.z, a.w);
  r.z = (int)pkbf(b.x, b.y); r.w = (int)pkbf(b.z, b.w);
  return r;
}

#define WAITV6() asm volatile("s_waitcnt vmcnt(6)" ::: "memory")
#define WAITV0() asm volatile("s_waitcnt vmcnt(0)" ::: "memory")
#define LGKM0() asm volatile("s_waitcnt lgkmcnt(0)" ::: "memory")
#define BAR() __builtin_amdgcn_s_barrier()
#define SCB() __builtin_amdgcn_sched_barrier(0)
#define PRIO1() __builtin_amdgcn_s_setprio(1)
#define PRIO0() __builtin_amdgcn_s_setprio(0)
#define VMBAR() do { WAITV0(); BAR(); } while (0)

// ---- cvtall: fp32->bf16 for x/Wi/Wo/Wg/Wu/Wd. Block = contiguous 16384-float chunk,
// ---- 16 batched float4 loads/thread, 8 x 16B stores. 1696 chunks. ----
__global__ __launch_bounds__(256) void cvtall_kernel(
    const float* __restrict__ x, const float* __restrict__ Wi, const float* __restrict__ Wo,
    const float* __restrict__ Wg, const float* __restrict__ Wu, const float* __restrict__ Wd,
    u16* __restrict__ xb, u16* __restrict__ Wib, u16* __restrict__ Wob,
    u16* __restrict__ Wgb, u16* __restrict__ Wub, u16* __restrict__ Wdb) {
  const int c = blockIdx.x, tid = threadIdx.x;
  const float* s; u16* d; int cs;
  if (c < 128) { s = x; d = xb; cs = 0; }
  else if (c < 144) { s = Wi; d = Wib; cs = 128; }
  else if (c < 160) { s = Wo; d = Wob; cs = 144; }
  else if (c < 672) { s = Wg; d = Wgb; cs = 160; }
  else if (c < 1184) { s = Wu; d = Wub; cs = 672; }
  else { s = Wd; d = Wdb; cs = 1184; }
  const size_t base = (size_t)(c - cs) * 16384 + (size_t)tid * 8;
  const float* sp = s + base;
  u16* dp = d + base;
  float4 a[16];
#pragma unroll
  for (int j = 0; j < 8; ++j) {
    a[2 * j] = *(const float4*)(sp + j * 2048);
    a[2 * j + 1] = *(const float4*)(sp + j * 2048 + 4);
  }
#pragma unroll
  for (int j = 0; j < 8; ++j)
    *(int4*)(dp + j * 2048) = pk8(a[2 * j], a[2 * j + 1]);
}

// ---------------- Wr_eff = W_router @ W_in (fp64, exact routing) ----------------
__global__ __launch_bounds__(256) void wreff_kernel(
    const float* __restrict__ Wr, const float* __restrict__ Wi, double* __restrict__ wre) {
  const int t = blockIdx.x * 256 + threadIdx.x;  // e*512+k
  const int e = t >> 9, k = t & 511;
  const float* wr = Wr + e * HDIM;
  double a0 = 0.0, a1 = 0.0, a2 = 0.0, a3 = 0.0;
  for (int j = 0; j < HDIM; j += 4) {
    a0 += (double)wr[j + 0] * (double)Wi[(j + 0) * HDIM + k];
    a1 += (double)wr[j + 1] * (double)Wi[(j + 1) * HDIM + k];
    a2 += (double)wr[j + 2] * (double)Wi[(j + 2) * HDIM + k];
    a3 += (double)wr[j + 3] * (double)Wi[(j + 3) * HDIM + k];
  }
  wre[t] = (a0 + a1) + (a2 + a3);
}

// ---------------- router: logits = x @ Wr_eff^T (fp64), softmax, top-2 ----------------
__global__ __launch_bounds__(128) void router_kernel(
    const float* __restrict__ x, const double* __restrict__ wre,
    int* __restrict__ idx, float* __restrict__ wts) {
  __shared__ double lw[NEXP * HDIM];  // 32 KB
  for (int i = threadIdx.x; i < NEXP * HDIM; i += 128) lw[i] = wre[i];
  __syncthreads();
  const int n = blockIdx.x * 128 + threadIdx.x;
  const float* xr = x + (size_t)n * HDIM;
  double acc[NEXP] = {};
  for (int k4 = 0; k4 < HDIM / 4; ++k4) {
    const float4 xv = ((const float4*)xr)[k4];
    const float xc[4] = {xv.x, xv.y, xv.z, xv.w};
#pragma unroll
    for (int c = 0; c < 4; ++c) {
      const double xd = (double)xc[c];
#pragma unroll
      for (int e = 0; e < NEXP; ++e) acc[e] += xd * lw[e * HDIM + k4 * 4 + c];
    }
  }
  double mx = acc[0];
#pragma unroll
  for (int e = 1; e < NEXP; ++e) mx = acc[e] > mx ? acc[e] : mx;
  double p[NEXP], se = 0.0;
#pragma unroll
  for (int e = 0; e < NEXP; ++e) { p[e] = exp(acc[e] - mx); se += p[e]; }
  const double inv = 1.0 / se;
#pragma unroll
  for (int e = 0; e < NEXP; ++e) p[e] *= inv;
  int i0 = 0; double b0 = p[0];
#pragma unroll
  for (int e = 1; e < NEXP; ++e) if (p[e] > b0) { b0 = p[e]; i0 = e; }
  int i1 = -1; double b1 = -1.0;
#pragma unroll
  for (int e = 0; e < NEXP; ++e) if (e != i0 && p[e] > b1) { b1 = p[e]; i1 = e; }
  const double e0 = exp(b0), e1 = exp(b1);  // softmax OF the top-2 probabilities
  idx[2 * n] = i0; idx[2 * n + 1] = i1;
  wts[2 * n] = (float)(e0 / (e0 + e1));
  wts[2 * n + 1] = (float)(e1 / (e0 + e1));
}

// ---------------- gather lists + 128-padded rowblock schedule ----------------
__global__ void assign_kernel(const int* __restrict__ idx, int* __restrict__ tok,
                              int* __restrict__ pos, int* __restrict__ rbe,
                              int* __restrict__ rbp, int* __restrict__ nrb) {
  __shared__ int cnt[NEXP], cur[NEXP];
  const int tid = threadIdx.x;
  if (tid < NEXP) cnt[tid] = 0;
  __syncthreads();
  for (int a = tid; a < NASSIGN; a += 256) atomicAdd(&cnt[idx[a]], 1);
  __syncthreads();
  if (tid == 0) {
    int o = 0, n = 0;
    for (int e = 0; e < NEXP; ++e) {
      cur[e] = o;
      const int nb = (cnt[e] + 127) >> 7;
      for (int i = 0; i < nb; ++i) { rbe[n] = e; rbp[n] = o + i * 128; ++n; }
      o += nb * 128;
    }
    nrb[0] = n;
  }
  __syncthreads();
  for (int p = tid; p < NPAD; p += 256) tok[p] = 0;  // pad rows -> token 0 (never read back)
  __syncthreads();
  for (int a = tid; a < NASSIGN; a += 256) {
    const int e = idx[a];
    const int q = atomicAdd(&cur[a >= 0 ? e : 0], 1);
    tok[q] = a >> 1;
    pos[a] = q;
  }
}

// ---- 128x64 BT GEMM body: 256 thr (4 waves of 64x32), 2-stage 48 KB -> 3 blocks/CU.
// ---- Same swizzle algebra + VMBAR schedule as the r3-proven 128x128 body. ----
template <int SB, int NT>
__device__ __forceinline__ void gemm64_body(
    const u16* __restrict__ A, const u16* __restrict__ B, void* __restrict__ C,
    int n0, int N, int K, u16* sm, int tid) {
  u16 *l0 = sm, *l1 = sm + 12288;  // per stage: A 8192 elems | B 4096 elems
  const int w = tid >> 6, l = tid & 63;
  const int wm = (w >> 1) * 64, wn = (w & 1) * 32;
  const int lm = l & 15, lk = (l >> 4) * 8, xr = (l & 7) << 3;
  const int sr = l >> 3, sc = ((l & 7) ^ sr) * 8;
  const u16* As = A + (size_t)(w * 8 + sr) * K + sc;
  const u16* Bs = B + (size_t)(n0 + w * 8 + sr) * K + sc;
  f32x4 acc[4][2] = {};
  auto STG = [&](u16* d, int kt) {  // 6 g2l16: A rows 0..127 (4 sweeps), B rows 0..63 (2)
#pragma unroll
    for (int c = 0; c < 4; ++c) g2l16(As + (size_t)(c * 32) * K + kt, d + c * 2048 + w * 512);
#pragma unroll
    for (int c = 0; c < 2; ++c)
      g2l16(Bs + (size_t)(c * 32) * K + kt, d + 8192 + c * 2048 + w * 512);
  };
  auto CMP = [&](const u16* a_, const u16* b_) {
#pragma unroll
    for (int kk = 0; kk < 2; ++kk) {
      const int ko = (kk * 32 + lk) ^ xr;
      bf16x8 af[4], bf[2];
#pragma unroll
      for (int i = 0; i < 4; ++i) af[i] = *(const bf16x8*)(a_ + (wm + i * 16 + lm) * 64 + ko);
#pragma unroll
      for (int j = 0; j < 2; ++j) bf[j] = *(const bf16x8*)(b_ + (wn + j * 16 + lm) * 64 + ko);
      PRIO1();
#pragma unroll
      for (int i = 0; i < 4; ++i)
#pragma unroll
        for (int j = 0; j < 2; ++j)
          acc[i][j] = __builtin_amdgcn_mfma_f32_16x16x32_bf16(af[i], bf[j], acc[i][j], 0, 0, 0);
      PRIO0();
    }
  };
  STG(l0, 0);
  VMBAR();
  for (int t = 0; t < NT; t += 2) {
    if (t + 1 < NT) STG(l1, (t + 1) * 64);
    CMP(l0, l0 + 8192);
    VMBAR();
    if (t + 2 < NT) STG(l0, (t + 2) * 64);
    CMP(l1, l1 + 8192);
    VMBAR();
  }
  const int cr = (l >> 4) * 4, cc = lm;
#pragma unroll
  for (int i = 0; i < 4; ++i)
#pragma unroll
    for (int j = 0; j < 2; ++j)
#pragma unroll
      for (int r = 0; r < 4; ++r) {
        const size_t o = (size_t)(wm + i * 16 + cr + r) * N + n0 + wn + j * 16 + cc;
        if (SB) ((u16*)C)[o] = f2bf(acc[i][j][r]);
        else ((float*)C)[o] = acc[i][j][r];
      }
}

__global__ __launch_bounds__(256, 3) void ingemm_kernel(
    const u16* __restrict__ xb, const u16* __restrict__ Wib, u16* __restrict__ hb) {
  __shared__ __align__(16) u16 sm[24576];  // 48 KB
  const int m0 = blockIdx.y * 128;
  gemm64_body<1, 8>(xb + (size_t)m0 * HDIM, Wib, hb + (size_t)m0 * HDIM,
                    blockIdx.x * 64, HDIM, HDIM, sm, threadIdx.x);
}

__global__ __launch_bounds__(256, 3) void outgemm_kernel(
    const u16* __restrict__ cb, const u16* __restrict__ Wob, float* __restrict__ out) {
  __shared__ __align__(16) u16 sm[24576];  // 48 KB
  const int m0 = blockIdx.y * 128;
  gemm64_body<0, 8>(cb + (size_t)m0 * HDIM, Wob, out + (size_t)m0 * HDIM,
                    blockIdx.x * 64, HDIM, HDIM, sm, threadIdx.x);
}

// ---- down: 128x64 tile, grid (8,72)=576 blocks, 3 blocks/CU (was 288 blocks @ ~1/CU) ----
__global__ __launch_bounds__(256, 3) void down_kernel(
    const u16* __restrict__ act, const u16* __restrict__ Wd, u16* __restrict__ dwn,
    const int* __restrict__ rbe, const int* __restrict__ rbp, const int* __restrict__ nrb) {
  const int rb = blockIdx.y;
  if (rb >= nrb[0]) return;
  __shared__ __align__(16) u16 sm[24576];  // 48 KB
  const int e = rbe[rb], p0 = rbp[rb];
  gemm64_body<1, 32>(act + (size_t)p0 * FDIM, Wd + (size_t)e * HDIM * FDIM,
                     dwn + (size_t)p0 * HDIM, blockIdx.x * 64, HDIM, FDIM, sm, threadIdx.x);
}

// ---- gateup (measured-stable 56-57us): 128 rows x (128G+128U), bf16 via g2l,
// ---- 3-buffer counted-vmcnt pipeline, 144 KB LDS ----
__global__ __launch_bounds__(512, 2) void gateup_kernel(
    const u16* __restrict__ hb, const u16* __restrict__ Wg, const u16* __restrict__ Wu,
    u16* __restrict__ act, const int* __restrict__ tok, const int* __restrict__ rbe,
    const int* __restrict__ rbp, const int* __restrict__ nrb) {
  const int rb = blockIdx.y;
  if (rb >= nrb[0]) return;
  __shared__ __align__(16) u16 sm[73728];  // 144 KB: 3 x (A 16K | G 16K | U 16K bytes)
  const int e = rbe[rb], p0 = rbp[rb], n0 = blockIdx.x * 128;
  const int tid = threadIdx.x, w = tid >> 6, l = tid & 63;
  const int wm = (w >> 2) * 64, wn = (w & 3) * 32;
  const int lm = l & 15, lk = (l >> 4) * 8, xr = (l & 7) << 3;
  const int sr = l >> 3, sc = ((l & 7) ^ sr) * 8;
  const u16* A0 = hb + (size_t)tok[p0 + w * 8 + sr] * HDIM + sc;
  const u16* A1 = hb + (size_t)tok[p0 + 64 + w * 8 + sr] * HDIM + sc;
  const u16* G0 = Wg + (size_t)e * FDIM * HDIM + (size_t)(n0 + w * 8 + sr) * HDIM + sc;
  const u16* G1 = G0 + (size_t)64 * HDIM;
  const u16* U0 = Wu + (size_t)e * FDIM * HDIM + (size_t)(n0 + w * 8 + sr) * HDIM + sc;
  const u16* U1 = U0 + (size_t)64 * HDIM;
  f32x4 ag[4][2] = {}, au[4][2] = {};
  auto STG = [&](int b, int kt) {  // 6 vmem instrs
    u16* d = sm + b * 24576;
    g2l16(A0 + kt, d + w * 512);
    g2l16(A1 + kt, d + 4096 + w * 512);
    g2l16(G0 + kt, d + 8192 + w * 512);
    g2l16(G1 + kt, d + 12288 + w * 512);
    g2l16(U0 + kt, d + 16384 + w * 512);
    g2l16(U1 + kt, d + 20480 + w * 512);
  };
  auto CMP = [&](int b) {
    const u16* a_ = sm + b * 24576;
    const u16* g_ = a_ + 8192;
    const u16* u_ = a_ + 16384;
#pragma unroll
    for (int kk = 0; kk < 2; ++kk) {
      const int ko = (kk * 32 + lk) ^ xr;
      bf16x8 af[4], gf[2], uf[2];
#pragma unroll
      for (int i = 0; i < 4; ++i) af[i] = *(const bf16x8*)(a_ + (wm + i * 16 + lm) * 64 + ko);
#pragma unroll
      for (int j = 0; j < 2; ++j) {
        gf[j] = *(const bf16x8*)(g_ + (wn + j * 16 + lm) * 64 + ko);
        uf[j] = *(const bf16x8*)(u_ + (wn + j * 16 + lm) * 64 + ko);
      }
#pragma unroll
      for (int i = 0; i < 4; ++i)
#pragma unroll
        for (int j = 0; j < 2; ++j) {
          ag[i][j] = __builtin_amdgcn_mfma_f32_16x16x32_bf16(af[i], gf[j], ag[i][j], 0, 0, 0);
          au[i][j] = __builtin_amdgcn_mfma_f32_16x16x32_bf16(af[i], uf[j], au[i][j], 0, 0, 0);
        }
    }
  };
  STG(0, 0); STG(1, 64);
  WAITV6(); BAR();  // stage 0 landed; stage 1 in flight
#pragma unroll
  for (int t = 0; t < 8; ++t) {
    if (t + 2 < 8) STG((t + 2) % 3, (t + 2) * 64);  // issue-early
    CMP(t % 3);
    if (t + 2 < 8) WAITV6(); else WAITV0();  // stage t+1 complete; newest stays in flight
    BAR();
  }
  const int cr = (l >> 4) * 4, cc = lm;
#pragma unroll
  for (int i = 0; i < 4; ++i)
#pragma unroll
    for (int j = 0; j < 2; ++j)
#pragma unroll
      for (int r = 0; r < 4; ++r) {
        const float g = ag[i][j][r], u = au[i][j][r];
        const float s = g / (1.0f + __expf(-g));
        act[(size_t)(p0 + wm + i * 16 + cr + r) * FDIM + n0 + wn + j * 16 + cc] = f2bf(s * u);
      }
}

// ---------------- combine: c[n] = w0*down[pos0] + w1*down[pos1] (bf16 in/out) ----------------
__global__ void combine_kernel(const u16* __restrict__ dwn, const int* __restrict__ pos,
                               const float* __restrict__ wts, u16* __restrict__ cb) {
  const int n = blockIdx.x, t = threadIdx.x;  // 128 threads x 4 elems
  const int p0 = pos[2 * n], p1 = pos[2 * n + 1];
  const float w0 = wts[2 * n], w1 = wts[2 * n + 1];
  const ushort4 a = ((const ushort4*)(dwn + (size_t)p0 * HDIM))[t];
  const ushort4 b = ((const ushort4*)(dwn + (size_t)p1 * HDIM))[t];
  ushort4 o;
  o.x = f2bf(w0 * bf2f(a.x) + w1 * bf2f(b.x));
  o.y = f2bf(w0 * bf2f(a.y) + w1 * bf2f(b.y));
  o.z = f2bf(w0 * bf2f(a.z) + w1 * bf2f(b.z));
  o.w = f2bf(w0 * bf2f(a.w) + w1 * bf2f(b.w));
  ((ushort4*)(cb + (size_t)n * HDIM))[t] = o;
}

extern "C" void kernel_launch(void* const* d_in, const int* in_sizes, int n_in,
                              void* d_out, int out_size, void* d_ws, size_t ws_size,
                              hipStream_t stream) {
  const float* x  = (const float*)d_in[0];
  const float* Wi = (const float*)d_in[1];
  const float* Wr = (const float*)d_in[2];
  const float* Wg = (const float*)d_in[3];
  const float* Wu = (const float*)d_in[4];
  const float* Wd = (const float*)d_in[5];
  const float* Wo = (const float*)d_in[6];
  float* out = (float*)d_out;

  char* ws = (char*)d_ws;
  size_t off = 0;
  auto alloc = [&](size_t bytes) -> void* {
    off = (off + 255) & ~(size_t)255;
    void* p = ws + off;
    off += bytes;
    return p;
  };
  u16* xb   = (u16*)alloc((size_t)NTOK * HDIM * 2);
  u16* hb   = (u16*)alloc((size_t)NTOK * HDIM * 2);
  u16* cb   = (u16*)alloc((size_t)NTOK * HDIM * 2);
  u16* Wib  = (u16*)alloc((size_t)HDIM * HDIM * 2);
  u16* Wob  = (u16*)alloc((size_t)HDIM * HDIM * 2);
  u16* Wgb  = (u16*)alloc((size_t)NEXP * FDIM * HDIM * 2);
  u16* Wub  = (u16*)alloc((size_t)NEXP * FDIM * HDIM * 2);
  u16* Wdb  = (u16*)alloc((size_t)NEXP * HDIM * FDIM * 2);
  u16* actb = (u16*)alloc((size_t)NPAD * FDIM * 2);
  u16* dwn  = (u16*)alloc((size_t)NPAD * HDIM * 2);
  double* wre = (double*)alloc((size_t)NEXP * HDIM * 8);
  int* idx = (int*)alloc((size_t)NASSIGN * 4);
  float* wts = (float*)alloc((size_t)NASSIGN * 4);
  int* tok = (int*)alloc((size_t)NPAD * 4);
  int* pos = (int*)alloc((size_t)NASSIGN * 4);
  int* rbe = (int*)alloc((size_t)RBMAX * 4);
  int* rbp = (int*)alloc((size_t)RBMAX * 4);
  int* nrb = (int*)alloc(256);

  cvtall_kernel<<<1696, 256, 0, stream>>>(x, Wi, Wo, Wg, Wu, Wd, xb, Wib, Wob, Wgb, Wub, Wdb);
  wreff_kernel<<<16, 256, 0, stream>>>(Wr, Wi, wre);
  router_kernel<<<32, 128, 0, stream>>>(x, wre, idx, wts);
  assign_kernel<<<1, 256, 0, stream>>>(idx, tok, pos, rbe, rbp, nrb);
  ingemm_kernel<<<dim3(8, 32), 256, 0, stream>>>(xb, Wib, hb);
  gateup_kernel<<<dim3(16, 72), 512, 0, stream>>>(hb, Wgb, Wub, actb, tok, rbe, rbp, nrb);
  down_kernel<<<dim3(8, 72), 256, 0, stream>>>(actb, Wdb, dwn, rbe, rbp, nrb);
  combine_kernel<<<NTOK, 128, 0, stream>>>(dwn, pos, wts, cb);
  outgemm_kernel<<<dim3(8, 32), 256, 0, stream>>>(cb, Wob, out);
}

// Round 10
// 235.155 us; speedup vs baseline: 1.0012x; 1.0012x over previous
//
#include <hip/hip_runtime.h>
#include <hip/hip_bf16.h>

typedef unsigned short u16;
typedef unsigned int u32;
typedef short bf16x8 __attribute__((ext_vector_type(8)));
typedef float f32x4 __attribute__((ext_vector_type(4)));

#define AS1 __attribute__((address_space(1)))
#define AS3 __attribute__((address_space(3)))

#define NTOK 4096
#define HDIM 512
#define FDIM 2048
#define NEXP 8
#define NASSIGN (NTOK * 2)
#define NPAD2 (NASSIGN + NEXP * 256)  // 10240 (256-pad space; 128-pad blocks live inside it)
#define RBMAX 128

__device__ __forceinline__ void g2l16(const void* g, void* l) {
  __builtin_amdgcn_global_load_lds((const AS1 u32*)g, (AS3 u32*)l, 16, 0, 0);
}
__device__ __forceinline__ u16 f2bf(float f) {  // RNE fp32->bf16
  u32 u = __float_as_uint(f);
  u = (u + 0x7FFFu + ((u >> 16) & 1u)) >> 16;
  return (u16)u;
}
__device__ __forceinline__ float bf2f(u16 h) { return __uint_as_float(((u32)h) << 16); }
__device__ __forceinline__ u32 pkbf(float a, float b) {
  __hip_bfloat162 h = __float22bfloat162_rn(float2{a, b});
  u32 r;
  __builtin_memcpy(&r, &h, 4);
  return r;
}
__device__ __forceinline__ int4 pk8(const float4 a, const float4 b) {
  int4 r;
  r.x = (int)pkbf(a.x, a.y); r.y = (int)pkbf(a.z, a.w);
  r.z = (int)pkbf(b.x, b.y); r.w = (int)pkbf(b.z, b.w);
  return r;
}

#define WAITV4() asm volatile("s_waitcnt vmcnt(4)" ::: "memory")
#define WAITV0() asm volatile("s_waitcnt vmcnt(0)" ::: "memory")
#define LGKM0() asm volatile("s_waitcnt lgkmcnt(0)" ::: "memory")
#define BAR() __builtin_amdgcn_s_barrier()
#define SCB() __builtin_amdgcn_sched_barrier(0)
#define PRIO1() __builtin_amdgcn_s_setprio(1)
#define PRIO0() __builtin_amdgcn_s_setprio(0)
#define VMBAR() do { WAITV0(); BAR(); } while (0)

// ---- cvtall (r8-proven <=55us): block = contiguous 16384-float chunk, 16 batched loads ----
__global__ __launch_bounds__(256) void cvtall_kernel(
    const float* __restrict__ x, const float* __restrict__ Wi, const float* __restrict__ Wo,
    const float* __restrict__ Wg, const float* __restrict__ Wu, const float* __restrict__ Wd,
    u16* __restrict__ xb, u16* __restrict__ Wib, u16* __restrict__ Wob,
    u16* __restrict__ Wgb, u16* __restrict__ Wub, u16* __restrict__ Wdb) {
  const int c = blockIdx.x, tid = threadIdx.x;
  const float* s; u16* d; int cs;
  if (c < 128) { s = x; d = xb; cs = 0; }
  else if (c < 144) { s = Wi; d = Wib; cs = 128; }
  else if (c < 160) { s = Wo; d = Wob; cs = 144; }
  else if (c < 672) { s = Wg; d = Wgb; cs = 160; }
  else if (c < 1184) { s = Wu; d = Wub; cs = 672; }
  else { s = Wd; d = Wdb; cs = 1184; }
  const size_t base = (size_t)(c - cs) * 16384 + (size_t)tid * 8;
  const float* sp = s + base;
  u16* dp = d + base;
  float4 a[16];
#pragma unroll
  for (int j = 0; j < 8; ++j) {
    a[2 * j] = *(const float4*)(sp + j * 2048);
    a[2 * j + 1] = *(const float4*)(sp + j * 2048 + 4);
  }
#pragma unroll
  for (int j = 0; j < 8; ++j)
    *(int4*)(dp + j * 2048) = pk8(a[2 * j], a[2 * j + 1]);
}

// ---------------- Wr_eff = W_router @ W_in (fp64, exact routing) ----------------
__global__ __launch_bounds__(256) void wreff_kernel(
    const float* __restrict__ Wr, const float* __restrict__ Wi, double* __restrict__ wre) {
  const int t = blockIdx.x * 256 + threadIdx.x;  // e*512+k
  const int e = t >> 9, k = t & 511;
  const float* wr = Wr + e * HDIM;
  double a0 = 0.0, a1 = 0.0, a2 = 0.0, a3 = 0.0;
  for (int j = 0; j < HDIM; j += 4) {
    a0 += (double)wr[j + 0] * (double)Wi[(j + 0) * HDIM + k];
    a1 += (double)wr[j + 1] * (double)Wi[(j + 1) * HDIM + k];
    a2 += (double)wr[j + 2] * (double)Wi[(j + 2) * HDIM + k];
    a3 += (double)wr[j + 3] * (double)Wi[(j + 3) * HDIM + k];
  }
  wre[t] = (a0 + a1) + (a2 + a3);
}

// ---------------- router: logits = x @ Wr_eff^T (fp64), softmax, top-2 ----------------
__global__ __launch_bounds__(128) void router_kernel(
    const float* __restrict__ x, const double* __restrict__ wre,
    int* __restrict__ idx, float* __restrict__ wts) {
  __shared__ double lw[NEXP * HDIM];  // 32 KB
  for (int i = threadIdx.x; i < NEXP * HDIM; i += 128) lw[i] = wre[i];
  __syncthreads();
  const int n = blockIdx.x * 128 + threadIdx.x;
  const float* xr = x + (size_t)n * HDIM;
  double acc[NEXP] = {};
  for (int k4 = 0; k4 < HDIM / 4; ++k4) {
    const float4 xv = ((const float4*)xr)[k4];
    const float xc[4] = {xv.x, xv.y, xv.z, xv.w};
#pragma unroll
    for (int c = 0; c < 4; ++c) {
      const double xd = (double)xc[c];
#pragma unroll
      for (int e = 0; e < NEXP; ++e) acc[e] += xd * lw[e * HDIM + k4 * 4 + c];
    }
  }
  double mx = acc[0];
#pragma unroll
  for (int e = 1; e < NEXP; ++e) mx = acc[e] > mx ? acc[e] : mx;
  double p[NEXP], se = 0.0;
#pragma unroll
  for (int e = 0; e < NEXP; ++e) { p[e] = exp(acc[e] - mx); se += p[e]; }
  const double inv = 1.0 / se;
#pragma unroll
  for (int e = 0; e < NEXP; ++e) p[e] *= inv;
  int i0 = 0; double b0 = p[0];
#pragma unroll
  for (int e = 1; e < NEXP; ++e) if (p[e] > b0) { b0 = p[e]; i0 = e; }
  int i1 = -1; double b1 = -1.0;
#pragma unroll
  for (int e = 0; e < NEXP; ++e) if (e != i0 && p[e] > b1) { b1 = p[e]; i1 = e; }
  const double e0 = exp(b0), e1 = exp(b1);  // softmax OF the top-2 probabilities
  idx[2 * n] = i0; idx[2 * n + 1] = i1;
  wts[2 * n] = (float)(e0 / (e0 + e1));
  wts[2 * n + 1] = (float)(e1 / (e0 + e1));
}

// ---- gather lists + dual rowblock schedules in 256-pad layout (r4-proven) ----
__global__ void assign_kernel(const int* __restrict__ idx, int* __restrict__ tok,
                              int* __restrict__ pos, int* __restrict__ rbe2,
                              int* __restrict__ rbp2, int* __restrict__ rbe1,
                              int* __restrict__ rbp1, int* __restrict__ nrb) {
  __shared__ int cnt[NEXP], cur[NEXP];
  const int tid = threadIdx.x;
  if (tid < NEXP) cnt[tid] = 0;
  __syncthreads();
  for (int a = tid; a < NASSIGN; a += 256) atomicAdd(&cnt[idx[a]], 1);
  __syncthreads();
  if (tid == 0) {
    int o = 0, n2 = 0, n1 = 0;
    for (int e = 0; e < NEXP; ++e) {
      cur[e] = o;
      const int nb2 = (cnt[e] + 255) >> 8;
      const int nb1 = (cnt[e] + 127) >> 7;
      for (int i = 0; i < nb2; ++i) { rbe2[n2] = e; rbp2[n2] = o + i * 256; ++n2; }
      for (int i = 0; i < nb1; ++i) { rbe1[n1] = e; rbp1[n1] = o + i * 128; ++n1; }
      o += nb2 * 256;
    }
    nrb[0] = n2; nrb[1] = n1;
  }
  __syncthreads();
  for (int p = tid; p < NPAD2; p += 256) tok[p] = 0;  // pad rows -> token 0 (never read back)
  __syncthreads();
  for (int a = tid; a < NASSIGN; a += 256) {
    const int e = idx[a];
    const int q = atomicAdd(&cur[e], 1);
    tok[q] = a >> 1;
    pos[a] = q;
  }
}

// ---------------- 128x128 BT GEMM body (r3-proven, part of the 218 best) ----------------
template <int SB, int NT>
__device__ __forceinline__ void gemm128_body(
    const u16* __restrict__ A, const u16* __restrict__ B, void* __restrict__ C,
    int m0, int n0, int N, int K, u16* sm, int tid) {
  u16 *lA0 = sm, *lA1 = sm + 8192, *lB0 = sm + 16384, *lB1 = sm + 24576;
  const int w = tid >> 6, l = tid & 63;
  const int wm = (w >> 2) * 64, wn = (w & 3) * 32;
  const int lm = l & 15, lk = (l >> 4) * 8, xr = (l & 7) << 3;
  const int sr = l >> 3, sc = ((l & 7) ^ sr) * 8;
  const u16* As = A + (size_t)(m0 + w * 8 + sr) * K + sc;
  const u16* Bs = B + (size_t)(n0 + w * 8 + sr) * K + sc;
  f32x4 acc[4][2] = {};
  auto STG = [&](u16* dA, u16* dB, int kt) {
    g2l16(As + kt, dA + w * 512);
    g2l16(As + (size_t)64 * K + kt, dA + 4096 + w * 512);
    g2l16(Bs + kt, dB + w * 512);
    g2l16(Bs + (size_t)64 * K + kt, dB + 4096 + w * 512);
  };
  auto CMP = [&](const u16* a_, const u16* b_) {
#pragma unroll
    for (int kk = 0; kk < 2; ++kk) {
      const int ko = (kk * 32 + lk) ^ xr;
      bf16x8 af[4], bf[2];
#pragma unroll
      for (int i = 0; i < 4; ++i) af[i] = *(const bf16x8*)(a_ + (wm + i * 16 + lm) * 64 + ko);
#pragma unroll
      for (int j = 0; j < 2; ++j) bf[j] = *(const bf16x8*)(b_ + (wn + j * 16 + lm) * 64 + ko);
      PRIO1();
#pragma unroll
      for (int i = 0; i < 4; ++i)
#pragma unroll
        for (int j = 0; j < 2; ++j)
          acc[i][j] = __builtin_amdgcn_mfma_f32_16x16x32_bf16(af[i], bf[j], acc[i][j], 0, 0, 0);
      PRIO0();
    }
  };
  STG(lA0, lB0, 0);
  VMBAR();
  for (int t = 0; t < NT; t += 2) {
    if (t + 1 < NT) STG(lA1, lB1, (t + 1) * 64);
    CMP(lA0, lB0);
    VMBAR();
    if (t + 2 < NT) STG(lA0, lB0, (t + 2) * 64);
    CMP(lA1, lB1);
    VMBAR();
  }
  const int cr = (l >> 4) * 4, cc = lm;
#pragma unroll
  for (int i = 0; i < 4; ++i)
#pragma unroll
    for (int j = 0; j < 2; ++j)
#pragma unroll
      for (int r = 0; r < 4; ++r) {
        const size_t o = (size_t)(m0 + wm + i * 16 + cr + r) * N + n0 + wn + j * 16 + cc;
        if (SB) ((u16*)C)[o] = f2bf(acc[i][j][r]);
        else ((float*)C)[o] = acc[i][j][r];
      }
}

__global__ __launch_bounds__(512, 2) void ingemm_kernel(
    const u16* __restrict__ xb, const u16* __restrict__ Wib, u16* __restrict__ hb) {
  __shared__ __align__(16) u16 sm[32768];  // 64 KB
  gemm128_body<1, 8>(xb, Wib, hb, blockIdx.y * 128, blockIdx.x * 128, HDIM, HDIM, sm, threadIdx.x);
}

__global__ __launch_bounds__(512, 2) void outgemm_kernel(
    const u16* __restrict__ cb, const u16* __restrict__ Wob, float* __restrict__ out) {
  __shared__ __align__(16) u16 sm[32768];  // 64 KB
  gemm128_body<0, 8>(cb, Wob, out, blockIdx.y * 128, blockIdx.x * 128, HDIM, HDIM, sm, threadIdx.x);
}

// ---- gateup v2: BM=256 x (128G+128U), 8 waves, WAVE-TILE 128x64 (43.7 FLOP/LDS-byte,
// ---- 2x round-9's ratio), BK=64, 2-stage 128 KB, epilogue G/U exchange via LDS ----
__global__ __launch_bounds__(512, 2) void gateup_kernel(
    const u16* __restrict__ hb, const u16* __restrict__ Wg, const u16* __restrict__ Wu,
    u16* __restrict__ act, const int* __restrict__ tok, const int* __restrict__ rbe2,
    const int* __restrict__ rbp2, const int* __restrict__ nrb) {
  const int rb = blockIdx.y;
  if (rb >= nrb[0]) return;
  __shared__ __align__(16) u16 sm[65536];  // 128 KB: 2 x (A 16384 | G 8192 | U 8192 elems)
  const int e = rbe2[rb], p0 = rbp2[rb], n0 = blockIdx.x * 128;
  const int tid = threadIdx.x, w = tid >> 6, l = tid & 63;
  const int half = w >> 2, rh = (w >> 1) & 1, ch = w & 1;  // G/U half, row-half, col-half
  const int lm = l & 15, lk = (l >> 4) * 8, xr = (l & 7) << 3;
  const int sr = l >> 3, sc = ((l & 7) ^ sr) * 8;  // pre-swizzled source col
  const u16* Asrc[4];
#pragma unroll
  for (int c = 0; c < 4; ++c)
    Asrc[c] = hb + (size_t)tok[p0 + c * 64 + w * 8 + sr] * HDIM + sc;
  const u16 *Gsrc[2], *Usrc[2];
#pragma unroll
  for (int c = 0; c < 2; ++c) {
    Gsrc[c] = Wg + (size_t)e * FDIM * HDIM + (size_t)(n0 + c * 64 + w * 8 + sr) * HDIM + sc;
    Usrc[c] = Wu + (size_t)e * FDIM * HDIM + (size_t)(n0 + c * 64 + w * 8 + sr) * HDIM + sc;
  }
  f32x4 acc[8][4] = {};  // 128 VGPR: wave's 128x64 tile of (G or U)
  auto STG = [&](int b, int kt) {  // 8 g2l16 per thread-sweep set
    u16* d = sm + b * 32768;
#pragma unroll
    for (int c = 0; c < 4; ++c) g2l16(Asrc[c] + kt, d + c * 4096 + w * 512);
#pragma unroll
    for (int c = 0; c < 2; ++c) {
      g2l16(Gsrc[c] + kt, d + 16384 + c * 4096 + w * 512);
      g2l16(Usrc[c] + kt, d + 24576 + c * 4096 + w * 512);
    }
  };
  auto CMP = [&](int b) {  // 24 ds_read_b128 + 64 MFMA per wave
    const u16* A_ = sm + b * 32768;
    const u16* B_ = A_ + 16384 + half * 8192;  // this wave's weight half (G or U)
#pragma unroll
    for (int kk = 0; kk < 2; ++kk) {
      const int ko = (kk * 32 + lk) ^ xr;
      bf16x8 af[8], bf[4];
#pragma unroll
      for (int i = 0; i < 8; ++i)
        af[i] = *(const bf16x8*)(A_ + (rh * 128 + i * 16 + lm) * 64 + ko);
#pragma unroll
      for (int j = 0; j < 4; ++j)
        bf[j] = *(const bf16x8*)(B_ + (ch * 64 + j * 16 + lm) * 64 + ko);
      PRIO1();
#pragma unroll
      for (int i = 0; i < 8; ++i)
#pragma unroll
        for (int j = 0; j < 4; ++j)
          acc[i][j] = __builtin_amdgcn_mfma_f32_16x16x32_bf16(af[i], bf[j], acc[i][j], 0, 0, 0);
      PRIO0();
    }
  };
  STG(0, 0);
  VMBAR();
#pragma unroll
  for (int t = 0; t < 8; ++t) {
    if (t < 7) STG((t + 1) & 1, (t + 1) * 64);
    CMP(t & 1);
    VMBAR();
  }
  // epilogue: U-waves publish their 128x64 f32 tiles; G-waves combine silu(g)*u and store
  const int cr = (l >> 4) * 4, cc = lm;
  float* red = (float*)sm;  // 32768 floats = 128 KB (stages dead)
  if (half == 1) {
#pragma unroll
    for (int i = 0; i < 8; ++i)
#pragma unroll
      for (int j = 0; j < 4; ++j)
        *(f32x4*)&red[(w - 4) * 8192 + (i * 4 + j) * 256 + l * 4] = acc[i][j];
  }
  LGKM0();
  BAR();
  if (half == 0) {
#pragma unroll
    for (int i = 0; i < 8; ++i)
#pragma unroll
      for (int j = 0; j < 4; ++j) {
        const f32x4 ua = *(const f32x4*)&red[w * 8192 + (i * 4 + j) * 256 + l * 4];
#pragma unroll
        for (int r = 0; r < 4; ++r) {
          const float g = acc[i][j][r], u = ua[r];
          const float s = g / (1.0f + __expf(-g));
          act[(size_t)(p0 + rh * 128 + i * 16 + cr + r) * FDIM + n0 + ch * 64 + j * 16 + cc] =
              f2bf(s * u);
        }
      }
  }
}

// ---- down (r3-proven kk-split 3-buffer, 96 KB) over the 128-pad schedule ----
__global__ __launch_bounds__(512, 2) void down_kernel(
    const u16* __restrict__ act, const u16* __restrict__ Wd, u16* __restrict__ dwn,
    const int* __restrict__ rbe1, const int* __restrict__ rbp1, const int* __restrict__ nrb) {
  const int rb = blockIdx.y;
  if (rb >= nrb[1]) return;
  __shared__ __align__(16) u16 sm[49152];  // 96 KB: 3 x (A 16K | B 16K bytes)
  const int e = rbe1[rb], p0 = rbp1[rb], n0 = blockIdx.x * 128;
  const int tid = threadIdx.x, w = tid >> 6, l = tid & 63;
  const int g = w >> 2;                         // kk-group: 0 -> k0..31, 1 -> k32..63
  const int wm = ((w >> 1) & 1) * 64, wn = (w & 1) * 64;
  const int lm = l & 15, lk = (l >> 4) * 8, xr = (l & 7) << 3;
  const int ko = (g * 32 + lk) ^ xr;
  const int sr = l >> 3, sc = ((l & 7) ^ sr) * 8;
  const u16* As = act + (size_t)(p0 + w * 8 + sr) * FDIM + sc;
  const u16* Bs = Wd + (size_t)e * HDIM * FDIM + (size_t)(n0 + w * 8 + sr) * FDIM + sc;
  f32x4 acc[4][4] = {};
  auto STG = [&](int b, int kt) {  // 4 vmem instrs
    u16* d = sm + b * 16384;
    g2l16(As + kt, d + w * 512);
    g2l16(As + (size_t)64 * FDIM + kt, d + 4096 + w * 512);
    g2l16(Bs + kt, d + 8192 + w * 512);
    g2l16(Bs + (size_t)64 * FDIM + kt, d + 12288 + w * 512);
  };
  auto CMP = [&](int b) {
    const u16* a_ = sm + b * 16384;
    const u16* b_ = a_ + 8192;
    bf16x8 af[4], bf[4];
#pragma unroll
    for (int i = 0; i < 4; ++i) af[i] = *(const bf16x8*)(a_ + (wm + i * 16 + lm) * 64 + ko);
#pragma unroll
    for (int j = 0; j < 4; ++j) bf[j] = *(const bf16x8*)(b_ + (wn + j * 16 + lm) * 64 + ko);
#pragma unroll
    for (int i = 0; i < 4; ++i)
#pragma unroll
      for (int j = 0; j < 4; ++j)
        acc[i][j] = __builtin_amdgcn_mfma_f32_16x16x32_bf16(af[i], bf[j], acc[i][j], 0, 0, 0);
  };
  STG(0, 0); STG(1, 64);
  WAITV4(); BAR();
#pragma unroll
  for (int t = 0; t < 32; ++t) {
    if (t + 2 < 32) STG((t + 2) % 3, (t + 2) * 64);
    CMP(t % 3);
    if (t + 2 < 32) WAITV4(); else WAITV0();
    BAR();
  }
  // partner-wave reduction: waves 4-7 (kk=1) dump partials; waves 0-3 add + store
  LGKM0();
  SCB();
  BAR();
  float* red = (float*)sm;
  if (g == 1) {
#pragma unroll
    for (int i = 0; i < 4; ++i)
#pragma unroll
      for (int j = 0; j < 4; ++j)
        *(f32x4*)&red[(w & 3) * 4096 + (i * 4 + j) * 256 + l * 4] = acc[i][j];
  }
  BAR();
  if (g == 0) {
    const int cr = (l >> 4) * 4, cc = lm;
#pragma unroll
    for (int i = 0; i < 4; ++i)
#pragma unroll
      for (int j = 0; j < 4; ++j) {
        const f32x4 o = *(const f32x4*)&red[w * 4096 + (i * 4 + j) * 256 + l * 4];
        const f32x4 s = acc[i][j] + o;
#pragma unroll
        for (int r = 0; r < 4; ++r)
          dwn[(size_t)(p0 + wm + i * 16 + cr + r) * HDIM + n0 + wn + j * 16 + cc] = f2bf(s[r]);
      }
  }
}

// ---------------- combine: c[n] = w0*down[pos0] + w1*down[pos1] (bf16 in/out) ----------------
__global__ void combine_kernel(const u16* __restrict__ dwn, const int* __restrict__ pos,
                               const float* __restrict__ wts, u16* __restrict__ cb) {
  const int n = blockIdx.x, t = threadIdx.x;  // 128 threads x 4 elems
  const int p0 = pos[2 * n], p1 = pos[2 * n + 1];
  const float w0 = wts[2 * n], w1 = wts[2 * n + 1];
  const ushort4 a = ((const ushort4*)(dwn + (size_t)p0 * HDIM))[t];
  const ushort4 b = ((const ushort4*)(dwn + (size_t)p1 * HDIM))[t];
  ushort4 o;
  o.x = f2bf(w0 * bf2f(a.x) + w1 * bf2f(b.x));
  o.y = f2bf(w0 * bf2f(a.y) + w1 * bf2f(b.y));
  o.z = f2bf(w0 * bf2f(a.z) + w1 * bf2f(b.z));
  o.w = f2bf(w0 * bf2f(a.w) + w1 * bf2f(b.w));
  ((ushort4*)(cb + (size_t)n * HDIM))[t] = o;
}

extern "C" void kernel_launch(void* const* d_in, const int* in_sizes, int n_in,
                              void* d_out, int out_size, void* d_ws, size_t ws_size,
                              hipStream_t stream) {
  const float* x  = (const float*)d_in[0];
  const float* Wi = (const float*)d_in[1];
  const float* Wr = (const float*)d_in[2];
  const float* Wg = (const float*)d_in[3];
  const float* Wu = (const float*)d_in[4];
  const float* Wd = (const float*)d_in[5];
  const float* Wo = (const float*)d_in[6];
  float* out = (float*)d_out;

  char* ws = (char*)d_ws;
  size_t off = 0;
  auto alloc = [&](size_t bytes) -> void* {
    off = (off + 255) & ~(size_t)255;
    void* p = ws + off;
    off += bytes;
    return p;
  };
  u16* xb   = (u16*)alloc((size_t)NTOK * HDIM * 2);
  u16* hb   = (u16*)alloc((size_t)NTOK * HDIM * 2);
  u16* cb   = (u16*)alloc((size_t)NTOK * HDIM * 2);
  u16* Wib  = (u16*)alloc((size_t)HDIM * HDIM * 2);
  u16* Wob  = (u16*)alloc((size_t)HDIM * HDIM * 2);
  u16* Wgb  = (u16*)alloc((size_t)NEXP * FDIM * HDIM * 2);
  u16* Wub  = (u16*)alloc((size_t)NEXP * FDIM * HDIM * 2);
  u16* Wdb  = (u16*)alloc((size_t)NEXP * HDIM * FDIM * 2);
  u16* actb = (u16*)alloc((size_t)NPAD2 * FDIM * 2);
  u16* dwn  = (u16*)alloc((size_t)NPAD2 * HDIM * 2);
  double* wre = (double*)alloc((size_t)NEXP * HDIM * 8);
  int* idx = (int*)alloc((size_t)NASSIGN * 4);
  float* wts = (float*)alloc((size_t)NASSIGN * 4);
  int* tok = (int*)alloc((size_t)NPAD2 * 4);
  int* pos = (int*)alloc((size_t)NASSIGN * 4);
  int* rbe2 = (int*)alloc((size_t)RBMAX * 4);
  int* rbp2 = (int*)alloc((size_t)RBMAX * 4);
  int* rbe1 = (int*)alloc((size_t)RBMAX * 4);
  int* rbp1 = (int*)alloc((size_t)RBMAX * 4);
  int* nrb = (int*)alloc(256);

  cvtall_kernel<<<1696, 256, 0, stream>>>(x, Wi, Wo, Wg, Wu, Wd, xb, Wib, Wob, Wgb, Wub, Wdb);
  wreff_kernel<<<16, 256, 0, stream>>>(Wr, Wi, wre);
  router_kernel<<<32, 128, 0, stream>>>(x, wre, idx, wts);
  assign_kernel<<<1, 256, 0, stream>>>(idx, tok, pos, rbe2, rbp2, rbe1, rbp1, nrb);
  ingemm_kernel<<<dim3(4, 32), 512, 0, stream>>>(xb, Wib, hb);
  gateup_kernel<<<dim3(16, 40), 512, 0, stream>>>(hb, Wgb, Wub, actb, tok, rbe2, rbp2, nrb);
  down_kernel<<<dim3(4, 72), 512, 0, stream>>>(actb, Wdb, dwn, rbe1, rbp1, nrb);
  combine_kernel<<<NTOK, 128, 0, stream>>>(dwn, pos, wts, cb);
  outgemm_kernel<<<dim3(4, 32), 512, 0, stream>>>(cb, Wob, out);
}